// Round 10
// baseline (229.021 us; speedup 1.0000x reference)
//
#include <hip/hip_runtime.h>
#include <hip/hip_bf16.h>
#include <hip/hip_cooperative_groups.h>

namespace cg = cooperative_groups;

// ConvexReLUCNN: B=512, C=3, H=W=64, KERNEL=3
//   K=27, L=62*62=3844, M=512, O=10
#define ODIM   10
#define HOg    62
#define LDIM   3844
#define CHW    12288
#define BATCH  512
#define KO     270
#define KOP    272        // ko padded to 17*16
#define MDIM   512        // reduction dim (neurons)

typedef __attribute__((ext_vector_type(8))) short bfrag;   // 8 bf16 (4 VGPR)
typedef __attribute__((ext_vector_type(4))) float f32x4;

// ---------------------------------------------------------------------------
// Single cooperative kernel, 256 blocks x 512 threads (1 block/CU).
// Phase 1: Gt = G^T (bf16), Pdt = (v-w)^T (bf16), S = 0.
// Phase 2: MFMA T-GEMM (round-8/9-verified fragments) + scatter-add into S.
// Phase 3: out[b][o] = sum_chw x[b][chw] * S[o][chw].
// grid.sync() between phases (harness supports cooperative launch).
// ---------------------------------------------------------------------------
__global__ __launch_bounds__(512)
void fused_kernel(const float* __restrict__ x,
                  const float* __restrict__ G,
                  const float* __restrict__ v,
                  const float* __restrict__ w,
                  float* __restrict__ out,
                  __hip_bfloat16* __restrict__ Gt,
                  __hip_bfloat16* __restrict__ Pdt,
                  float* __restrict__ S) {
    cg::grid_group grid = cg::this_grid();
    const int bid = blockIdx.x;
    const int tid = threadIdx.x;

    __shared__ float trt[2][64][65];      // phase-1 transpose staging (33 KB)
    __shared__ float red[8][2 * ODIM];    // phase-3 reduction

    // ================= Phase 1: prep =================
    // 1512 quarter-units packed as 756 half-block units (two 256-thr groups).
    // Unit classes are aligned so both groups of a block take the same path
    // (Gt: ou<488 even-split at u=243; Pdt: 488..1031; S-zero: 1032..1511).
    {
        const int sub  = tid >> 8;        // 0/1: which 256-thr group
        const int t256 = tid & 255;
        for (int u = bid; u < 756; u += 256) {
            int ou = u * 2 + sub;
            if (ou < 488) {
                // --- Gt transpose tile (64n x 64m) ---
                const int nTile = ou % 61;
                const int mTile = ou / 61;         // 0..7
                const int n0 = nTile * 64;
                const int m0 = mTile * 64;
                const int tc = t256 & 63;
                const int tr = t256 >> 6;
#pragma unroll
                for (int rr = 0; rr < 64; rr += 4) {
                    int n = n0 + tc;
                    trt[sub][rr + tr][tc] =
                        (n < LDIM) ? G[(size_t)(m0 + rr + tr) * LDIM + n] : 0.f;
                }
                __syncthreads();
                const int nr = t256 >> 2;          // n-row within tile
                const int ms = (t256 & 3) * 16;    // m-segment
                __hip_bfloat16 buf[16];
#pragma unroll
                for (int i = 0; i < 16; ++i)
                    buf[i] = __float2bfloat16(trt[sub][ms + i][nr]);
                __hip_bfloat16* dst = Gt + (size_t)(n0 + nr) * MDIM + m0 + ms;
                *reinterpret_cast<uint4*>(dst)     = *reinterpret_cast<uint4*>(&buf[0]);
                *reinterpret_cast<uint4*>(dst + 8) = *reinterpret_cast<uint4*>(&buf[8]);
                __syncthreads();   // protect trt before next loop iteration
            } else if (ou < 1032) {
                // --- Pdt ---
                int idx = (ou - 488) * 256 + t256;   // m*KOP + ko (exact range)
                int m  = idx / KOP;
                int ko = idx - m * KOP;
                float val = (ko < KO) ? (v[m * KO + ko] - w[m * KO + ko]) : 0.f;
                Pdt[(size_t)ko * MDIM + m] = __float2bfloat16(val);
            } else {
                // --- S zero ---
                int idx = (ou - 1032) * 256 + t256;  // 122880 exact
                S[idx] = 0.f;
            }
        }
    }

    __threadfence();
    grid.sync();

    // ================= Phase 2: MFMA T-GEMM + scatter into S =================
    // 1037 wave-units = (kt 0..16) x (tile 0..60); unit u = wv*256 + bid so
    // every block (CU) gets MFMA work on waves 0..3(4).
    {
        const int wv   = tid >> 6;
        const int lane = tid & 63;
        const int u    = wv * 256 + bid;
        if (u < 17 * 61) {
            const int kt = u % 17;
            const int tl = u / 17;          // 0..60
            const int n0  = tl * 64;
            const int ko0 = kt * 16;
            const int row = lane & 15;
            const int kg  = lane >> 4;      // 0..3

            const __hip_bfloat16* Ap = Pdt + (size_t)(ko0 + row) * MDIM + kg * 8;
            const __hip_bfloat16* Bp = Gt  + (size_t)(n0 + row) * MDIM + kg * 8;

            bfrag a[16];
#pragma unroll
            for (int ks = 0; ks < 16; ++ks)
                a[ks] = *reinterpret_cast<const bfrag*>(Ap + ks * 32);

            f32x4 acc[4];
#pragma unroll
            for (int j = 0; j < 4; ++j) acc[j] = (f32x4){0.f, 0.f, 0.f, 0.f};

#pragma unroll 4
            for (int ks = 0; ks < 16; ++ks) {
#pragma unroll
                for (int j = 0; j < 4; ++j) {
                    bfrag bfr = *reinterpret_cast<const bfrag*>(
                        Bp + (size_t)j * 16 * MDIM + ks * 32);
                    acc[j] = __builtin_amdgcn_mfma_f32_16x16x32_bf16(a[ks], bfr, acc[j], 0, 0, 0);
                }
            }

            // scatter-add into S (each (ko,n) -> exactly one S element)
            int sbase[4];
            bool kval[4];
#pragma unroll
            for (int r = 0; r < 4; ++r) {
                int ko = ko0 + kg * 4 + r;
                kval[r] = (ko < KO);
                int kc  = kval[r] ? ko : 0;
                int o   = kc % ODIM;
                int rem = kc / ODIM;          // 0..26
                int c   = rem / 9;
                int ij  = rem - c * 9;
                int i   = ij / 3;
                int jk  = ij - i * 3;
                sbase[r] = o * CHW + c * 4096 + i * 64 + jk;
            }
#pragma unroll
            for (int j = 0; j < 4; ++j) {
                int col = n0 + j * 16 + row;
                if (col < LDIM) {
                    int pi  = col / HOg;
                    int pj  = col - pi * HOg;
                    int off = pi * 64 + pj;
#pragma unroll
                    for (int r = 0; r < 4; ++r) {
                        if (kval[r])
                            atomicAdd(&S[sbase[r] + off], acc[j][r]);
                    }
                }
            }
        }
    }

    __threadfence();
    grid.sync();
    __threadfence();

    // ================= Phase 3: out = x . S =================
    {
        const int b0 = bid * 2;
        const int NV = CHW / 4;   // 3072
        const float4* X0 = reinterpret_cast<const float4*>(x) + (size_t)b0 * NV;
        const float4* X1 = X0 + NV;
        const float4* S4 = reinterpret_cast<const float4*>(S);

        float acc0[ODIM], acc1[ODIM];
#pragma unroll
        for (int o = 0; o < ODIM; ++o) { acc0[o] = 0.f; acc1[o] = 0.f; }

        for (int i = tid; i < NV; i += 512) {
            float4 a = X0[i];
            float4 b = X1[i];
#pragma unroll
            for (int o = 0; o < ODIM; ++o) {
                float4 sv = S4[(size_t)o * NV + i];
                acc0[o] += a.x * sv.x + a.y * sv.y + a.z * sv.z + a.w * sv.w;
                acc1[o] += b.x * sv.x + b.y * sv.y + b.z * sv.z + b.w * sv.w;
            }
        }

#pragma unroll
        for (int o = 0; o < ODIM; ++o) {
            float s0 = acc0[o], s1 = acc1[o];
            for (int off = 32; off > 0; off >>= 1) {
                s0 += __shfl_down(s0, off, 64);
                s1 += __shfl_down(s1, off, 64);
            }
            acc0[o] = s0; acc1[o] = s1;
        }

        const int wvv = tid >> 6;
        const int ln  = tid & 63;
        if (ln == 0) {
#pragma unroll
            for (int o = 0; o < ODIM; ++o) {
                red[wvv][o]        = acc0[o];
                red[wvv][ODIM + o] = acc1[o];
            }
        }
        __syncthreads();
        if (tid < 2 * ODIM) {
            float tsum = 0.f;
#pragma unroll
            for (int wvi = 0; wvi < 8; ++wvi) tsum += red[wvi][tid];
            int bt = tid / ODIM;
            int o  = tid - bt * ODIM;
            out[(size_t)(b0 + bt) * ODIM + o] = tsum;
        }
    }
}

extern "C" void kernel_launch(void* const* d_in, const int* in_sizes, int n_in,
                              void* d_out, int out_size, void* d_ws, size_t ws_size,
                              hipStream_t stream) {
    const float* x = (const float*)d_in[0];   // (512, 3, 64, 64)
    const float* G = (const float*)d_in[1];   // (512, 3844)
    const float* v = (const float*)d_in[2];   // (512, 27, 10)
    const float* w = (const float*)d_in[3];   // (512, 27, 10)
    float* out = (float*)d_out;               // (512, 10)

    // ws layout:
    //   S   fp32 [10][12288] =   491,520 B   (atomic-accumulated)
    //   Gt  bf16 [3904][512] = 3,997,696 B
    //   Pdt bf16 [272][512]  =   278,528 B
    char* wsb = (char*)d_ws;
    float*          S   = (float*)wsb;
    __hip_bfloat16* Gt  = (__hip_bfloat16*)(wsb + 491520);
    __hip_bfloat16* Pdt = (__hip_bfloat16*)(wsb + 491520 + 3997696);

    void* args[] = { (void*)&x, (void*)&G, (void*)&v, (void*)&w,
                     (void*)&out, (void*)&Gt, (void*)&Pdt, (void*)&S };
    hipLaunchCooperativeKernel(reinterpret_cast<void*>(fused_kernel),
                               dim3(256), dim3(512), args, 0, stream);
}